// Round 11
// baseline (361.551 us; speedup 1.0000x reference)
//
#include <hip/hip_runtime.h>
#include <stdint.h>

#define NB 8
#define LL 128
#define NS 1928      // number of spans (l,r), r-l+1 <= 16
#define NK 10        // top-k
#define WPB 4        // waves (spans) per block

// span id for (l, r): offset(l) + (r-l)
__device__ __forceinline__ int span_id(int l, int r) {
    int off = (l <= 112) ? (l << 4) : (NS - (((128 - l) * (129 - l)) >> 1));
    return off + (r - l);
}

// Replica of numpy's SIMD float32 exp (verified exact vs oracle in R9/R10).
__device__ __forceinline__ float npexp_f32(float x) {
    const float magic = 12582912.0f;
    const float log2e = 1.442695040888963f;
    const float c1 = -6.93145752e-1f;
    const float c2 = -1.42860677e-6f;
    float t = __fmul_rn(x, log2e);
    float q = __fsub_rn(__fadd_rn(t, magic), magic);
    float r = __fmaf_rn(q, c1, x);
    r = __fmaf_rn(q, c2, r);
    float num = __fmaf_rn(r, 5.082762527590693718096e-04f, 6.757896990527504603057e-03f);
    num = __fmaf_rn(num, r, 5.114512081637298353406e-02f);
    num = __fmaf_rn(num, r, 2.473615434895520810817e-01f);
    num = __fmaf_rn(num, r, 7.257664613233124478488e-01f);
    num = __fmaf_rn(num, r, 9.999999999980870924916e-01f);
    float den = __fmaf_rn(r, 2.159509375685829852307e-02f, -2.742335390411667452936e-01f);
    den = __fmaf_rn(den, r, 1.0f);
    float p = __fdiv_rn(num, den);
    int qi = (int)q;
    return __fmul_rn(p, __int_as_float((127 + qi) << 23));
}

__device__ __forceinline__ float keyval(unsigned long long k) {
    return __uint_as_float((unsigned)(k >> 32));
}

__device__ __forceinline__ void wfence() {
    __builtin_amdgcn_wave_barrier();
    __threadfence_block();
    __builtin_amdgcn_wave_barrier();
}

// r-th (0-based) set bit of m (m has > r set bits)
__device__ __forceinline__ int sel_bit(unsigned long long m, int r) {
    int pos = 0;
#pragma unroll
    for (int w = 32; w >= 1; w >>= 1) {
        int c = __popcll(m & ((1ull << w) - 1ull));
        if (r >= c) { r -= c; m >>= w; pos += w; }
    }
    return pos;
}

// Wave-parallel emulation of numpy aquicksort's partition step (R10-verified).
__device__ int wave_partition(unsigned long long* a, int pl, int pr, int lane) {
    int pm = pl + ((pr - pl) >> 1);
    unsigned long long vl = a[pl], vm = a[pm], vr = a[pr], tt;
    if (keyval(vm) < keyval(vl)) { tt = vm; vm = vl; vl = tt; }
    if (keyval(vr) < keyval(vm)) { tt = vr; vr = vm; vm = tt; }
    if (keyval(vm) < keyval(vl)) { tt = vm; vm = vl; vl = tt; }
    float vp = keyval(vm);
    unsigned long long vq = a[pr - 1];
    if (lane == 0) { a[pl] = vl; a[pr] = vr; a[pm] = vq; a[pr - 1] = vm; }
    wfence();

    int n = pr - pl + 1;
    int nch = (n + 63) >> 6;
    unsigned long long mge = 0ull, mle = 0ull;
    for (int c = 0; c < nch; ++c) {
        int pos = pl + (c << 6) + lane;
        bool inr = (pos <= pr);
        float v = inr ? keyval(a[pos]) : 0.0f;
        bool ge = inr && (pos > pl) && (pos < pr) && (v >= vp);
        bool le = inr && (pos <= pr - 2) && (v <= vp);
        unsigned long long bge = __ballot(ge);
        unsigned long long ble = __ballot(le);
        if (lane == c) { mge = bge; mle = ble; }
    }
    int cge = __popcll(mge), cle = __popcll(mle);
    int ige = cge, ile = cle;
    for (int off = 1; off < 64; off <<= 1) {
        int xg = __shfl_up(ige, off, 64);
        int xl = __shfl_up(ile, off, 64);
        if (lane >= off) { ige += xg; ile += xl; }
    }
    int totGE = __shfl(ige, 63, 64);
    int totLE = __shfl(ile, 63, 64);
    int ege = ige - cge, ele = ile - cle;

    auto selL = [&](int k) -> int {
        int c = 0, e0 = 0;
        for (int cc = 0; cc < nch; ++cc) {
            int e = __shfl(ege, cc, 64);
            int cnt = __shfl(cge, cc, 64);
            if (k >= e && k < e + cnt) { c = cc; e0 = e; }
        }
        unsigned long long m = __shfl(mge, c, 64);
        return pl + (c << 6) + sel_bit(m, k - e0);
    };
    auto selR = [&](int k) -> int {
        int c = 0, r = 0;
        for (int cc = 0; cc < nch; ++cc) {
            int e = __shfl(ele, cc, 64);
            int cnt = __shfl(cle, cc, 64);
            int above = totLE - e - cnt;
            if (k >= above && k < above + cnt) { c = cc; r = cnt - 1 - (k - above); }
        }
        unsigned long long m = __shfl(mle, c, 64);
        return pl + (c << 6) + sel_bit(m, r);
    };

    int K = 0;
    int maxk = (totGE < totLE) ? totGE : totLE;
    for (int base = 0;; base += 64) {
        int k = base + lane;
        bool active = (k < maxk);
        int kq = active ? k : 0;
        int Lk = selL(kq);
        int Rk = selR(kq);
        bool sw = active && (Lk < Rk);
        unsigned long long bm = __ballot(sw);
        int nsw = (~bm == 0ull) ? 64 : (__ffsll((long long)~bm) - 1);
        if (sw && (lane < nsw)) {
            unsigned long long tl = a[Lk], tr = a[Rk];
            a[Lk] = tr; a[Rk] = tl;
        }
        K += nsw;
        if (nsw < 64) break;
    }
    wfence();
    int pi = selL(K);
    if (K > 0) { int rp = selR(K - 1); if (rp < pi) pi = rp; }
    if (lane == 0) { tt = a[pi]; a[pi] = a[pr - 1]; a[pr - 1] = tt; }
    wfence();
    return pi;
}

__device__ __forceinline__ void lane_sift(unsigned long long* h, int start, int hm) {
    unsigned long long tmp = h[start];
    int i = start, j = start + start;
    while (j <= hm) {
        if (j < hm && keyval(h[j]) < keyval(h[j + 1])) ++j;
        if (keyval(tmp) < keyval(h[j])) { h[i] = h[j]; i = j; j += j; }
        else break;
    }
    h[i] = tmp;
}

__device__ void wave_heap_top(unsigned long long* a, int lo, int hi, int needlo, int lane) {
    unsigned long long* h = a + lo - 1;
    int hm = hi - lo + 1;
    int half = hm >> 1;
    int maxlvl = 0; { int v = half; while (v >>= 1) ++maxlvl; }
    for (int lvl = maxlvl; lvl >= 0; --lvl) {
        int n0 = 1 << lvl;
        int n1 = (n0 << 1) - 1; if (n1 > half) n1 = half;
        for (int nb = n0; nb <= n1; nb += 64) {
            int node = nb + lane;
            if (node <= n1) lane_sift(h, node, hm);
        }
        wfence();
    }
    int E = hi - needlo + 1;
    if (E > hm - 1) E = hm - 1;
    if (lane == 0) {
        int m = hm;
        for (int e = 0; e < E; ++e) {
            unsigned long long tmp = h[m]; h[m] = h[1]; --m;
            int i = 1, j = 2;
            while (j <= m) {
                if (j < m && keyval(h[j]) < keyval(h[j + 1])) ++j;
                if (keyval(tmp) < keyval(h[j])) { h[i] = h[j]; i = j; j += j; }
                else break;
            }
            h[i] = tmp;
        }
    }
    wfence();
}

__device__ void wave_insertion(unsigned long long* a, int lo, int hi, int lane) {
    int len = hi - lo + 1;
    unsigned long long v = (lane < len) ? a[lo + lane] : 0ull;
    float fv = keyval(v);
    int rank = 0;
    for (int j = 0; j < len; ++j) {
        unsigned long long vj = __shfl(v, j, 64);
        float fj = keyval(vj);
        if ((fj < fv) || (fj == fv && j < lane)) ++rank;
    }
    wfence();
    if (lane < len) a[lo + rank] = v;
    wfence();
}

__device__ void wave_np_sort_top(unsigned long long* a, int n, int lane, int* stk) {
    int depth = 0; { int v = n; while (v >>= 1) ++depth; }
    depth *= 2;
    const int TOPLO = n - NK;
    int sp = 0;
    int lo = 0, hi = n - 1;
    for (;;) {
        while (hi - lo > 15) {
            if (depth-- < 0) {
                if (hi >= TOPLO) wave_heap_top(a, lo, hi, (lo > TOPLO ? lo : TOPLO), lane);
                goto pop;
            }
            {
                int pi = wave_partition(a, lo, hi, lane);
                if (pi - lo < hi - pi) {
                    if (lane == 0) { stk[sp * 2] = pi + 1; stk[sp * 2 + 1] = hi; }
                    ++sp; hi = pi - 1;
                } else {
                    if (lane == 0) { stk[sp * 2] = lo; stk[sp * 2 + 1] = pi - 1; }
                    ++sp; lo = pi + 1;
                }
                wfence();
            }
        }
        if (hi > lo && hi >= TOPLO) wave_insertion(a, lo, hi, lane);
pop:
        if (sp == 0) break;
        --sp;
        lo = stk[sp * 2]; hi = stk[sp * 2 + 1];
    }
}

// Kernel 1: per (b,t) extract raw top1 head index, zero flags
__global__ void top1_kernel(const int* __restrict__ hi,
                            unsigned char* __restrict__ top1,
                            unsigned char* __restrict__ flags) {
    int tid = blockIdx.x * blockDim.x + threadIdx.x;
    if (tid >= NB * NS) return;
    int b = tid / NS, t = tid - b * NS;
    int l, r;
    if (t < 1808) { l = t >> 4; r = l + (t & 15); }
    else {
        l = 113;
        while (l < 127 && span_id(l + 1, l + 1) <= t) ++l;
        r = l + (t - span_id(l, l));
    }
    int i0 = hi[((b * LL + l) * LL + r) * 4];
    top1[b * NS + t] = (unsigned char)(i0 & 127);
    flags[b * NS + t] = 0;
}

// Kernel 2: one wave per (b,l) — cumsum cap
__global__ void cap_kernel(const unsigned char* __restrict__ top1,
                           unsigned char* __restrict__ flags) {
    int gw = (blockIdx.x * blockDim.x + threadIdx.x) >> 6;
    int lane = threadIdx.x & 63;
    int b = gw >> 7, l = gw & 127;
    const unsigned char* tb = top1 + b * NS;
    unsigned char* fb = flags + b * NS;
    int cnt = 0;
    for (int t0 = 0; t0 < NS; t0 += 64) {
        int t = t0 + lane;
        int tp = (t < NS) ? (int)tb[t] : 255;
        bool match = (tp == l);
        unsigned long long m = __ballot(match);
        if (match) {
            int pre = __popcll(m & ((1ull << lane) - 1ull));
            fb[t] = (cnt + pre + 1 <= 128) ? 1 : 0;
        }
        cnt += __popcll(m);
    }
}

// Shared stage-1 staging body (A and B): pack {W0,W1,W2,rec} + lrc
__device__ __forceinline__ void stage_tables(const int* hb, const float* wb,
                                             const unsigned char* fb,
                                             float4* s_pack, uint16_t* s_lrc) {
    for (int j = threadIdx.x; j < LL * 16; j += 256) {
        int l = j >> 4, w = j & 15, r = l + w;
        if (r < LL) {
            int sid = span_id(l, r);
            int4 iv = *(const int4*)(hb + (l * LL + r) * 4);
            float4 wv = *(const float4*)(wb + (l * LL + r) * 4);
            int ia = iv.x, ib = iv.y, ic = iv.z;
            float wa = wv.x, wb2 = wv.y, wc = wv.z;
            int m0, m1 = 255, m2 = 255;
            float W0, W1 = 0.f, W2 = 0.f;
            if (ia == ib && ib == ic) {
                m0 = ia; W0 = __fadd_rn(__fadd_rn(wa, wb2), wc);
            } else if (ia == ib) {
                float W = __fadd_rn(wa, wb2);
                if (ia < ic) { m0 = ia; W0 = W; m1 = ic; W1 = wc; }
                else         { m0 = ic; W0 = wc; m1 = ia; W1 = W; }
            } else if (ia == ic) {
                float W = __fadd_rn(wa, wc);
                if (ia < ib) { m0 = ia; W0 = W; m1 = ib; W1 = wb2; }
                else         { m0 = ib; W0 = wb2; m1 = ia; W1 = W; }
            } else if (ib == ic) {
                float W = __fadd_rn(wb2, wc);
                if (ia < ib) { m0 = ia; W0 = wa; m1 = ib; W1 = W; }
                else         { m0 = ib; W0 = W; m1 = ia; W1 = wa; }
            } else {
                int x0 = ia, x1 = ib, x2 = ic; float y0 = wa, y1 = wb2, y2 = wc;
                if (x0 > x1) { int tx = x0; x0 = x1; x1 = tx; float ty = y0; y0 = y1; y1 = ty; }
                if (x1 > x2) { int tx = x1; x1 = x2; x2 = tx; float ty = y1; y1 = y2; y2 = ty; }
                if (x0 > x1) { int tx = x0; x0 = x1; x1 = tx; float ty = y0; y0 = y1; y1 = ty; }
                m0 = x0; m1 = x1; m2 = x2; W0 = y0; W1 = y1; W2 = y2;
            }
            uint32_t cap = fb[sid] & 1u;
            uint32_t rec = (uint32_t)m0 | ((uint32_t)m1 << 8) | ((uint32_t)m2 << 16)
                         | ((uint32_t)(ia & 127) << 24);
            s_pack[sid] = make_float4(W0, W1, W2, __uint_as_float(rec));
            s_lrc[sid] = (uint16_t)(l | (r << 7) | (cap << 14));
        }
    }
}

// Kernel A: fast path — lane-sorted wave top-11, flags tie rows for kernel B
__global__ __launch_bounds__(256)
void span_scan_kernel(const int* __restrict__ hi, const float* __restrict__ hw,
                      const float* __restrict__ dist,
                      const unsigned char* __restrict__ capf,
                      unsigned char* __restrict__ rowflag,
                      int* __restrict__ out) {
    __shared__ float4 s_pack[NS];
    __shared__ uint16_t s_lrc[NS];
    __shared__ float s_q[WPB][LL];

    const int b = blockIdx.y;
    stage_tables(hi + b * LL * LL * 4, hw + b * LL * LL * 4, capf + b * NS, s_pack, s_lrc);
    __syncthreads();

    const int wid = threadIdx.x >> 6;
    const int lane = threadIdx.x & 63;
    const int s = blockIdx.x * WPB + wid;

    // Stage 2: q row (ascending-index FMA chain from 0) + coverage ballots
    float4 ps = s_pack[s];
    uint32_t rec = __float_as_uint(ps.w);
    int m0 = rec & 255, m1 = (rec >> 8) & 255, m2 = (rec >> 16) & 255;
    bool e1 = (m1 != 255), e2 = (m2 != 255);
    uint32_t lrc = s_lrc[s];
    int ls = lrc & 127, rs = (lrc >> 7) & 127;

    const float* db = dist + b * LL * LL;
    const float* row0 = db + m0 * LL;
    const float* row1 = db + (e1 ? m1 : 0) * LL;
    const float* row2 = db + (e2 ? m2 : 0) * LL;
    int mA = lane, mB = lane + 64;
    float dA0 = row0[mA], dB0 = row0[mB];
    float dA1 = row1[mA], dB1 = row1[mB];
    float dA2 = row2[mA], dB2 = row2[mB];
    float qA = __fmaf_rn(ps.x, npexp_f32(-dA0), 0.0f);
    qA = __fmaf_rn(ps.y, npexp_f32(-dA1), qA);
    qA = __fmaf_rn(ps.z, npexp_f32(-dA2), qA);
    float qB = __fmaf_rn(ps.x, npexp_f32(-dB0), 0.0f);
    qB = __fmaf_rn(ps.y, npexp_f32(-dB1), qB);
    qB = __fmaf_rn(ps.z, npexp_f32(-dB2), qB);
    bool cA = (dA0 <= 2.0f || mA == m0) ||
              (e1 && (dA1 <= 2.0f || mA == m1)) ||
              (e2 && (dA2 <= 2.0f || mA == m2));
    bool cB = (dB0 <= 2.0f || mB == m0) ||
              (e1 && (dB1 <= 2.0f || mB == m1)) ||
              (e2 && (dB2 <= 2.0f || mB == m2));
    unsigned long long ub0 = __ballot(cA);
    unsigned long long ub1 = __ballot(cB);
    s_q[wid][mA] = qA;
    s_q[wid][mB] = qB;
    const float* q = s_q[wid];

    // Stage 3: scan with wave-cooperative sorted top-11 (one rank per lane, desc).
    // v[lane 0..10] = rank-(lane+1) gate bits; tau = rank-11 value (wave-uniform).
    unsigned v = 0u; int vi = -1; unsigned tau = 0u;

    for (int t0 = 0; t0 < NS; t0 += 64) {
        int t = t0 + lane;
        unsigned key = 0u;
        if (t < NS) {
            float4 pt = s_pack[t];
            uint32_t rt = __float_as_uint(pt.w);
            float g = __fmaf_rn(pt.x, q[rt & 127], 0.0f);
            g = __fmaf_rn(pt.y, q[(rt >> 8) & 127], g);
            g = __fmaf_rn(pt.z, q[(rt >> 16) & 127], g);
            uint32_t lr = s_lrc[t];
            int lt = lr & 127, rt2 = (lr >> 7) & 127;
            int dl = lt - ls; if (dl < 0) dl = -dl;
            int dr = rt2 - rs; if (dr < 0) dr = -dr;
            bool neq = (t != s);
            bool geom = neq && (dl <= 1) && (dr <= 1);
            int ri0 = rt >> 24;
            unsigned long long bits = (ri0 & 64) ? ub1 : ub0;
            bool um = (((bits >> (ri0 & 63)) & 1ull) != 0) && ((lr >> 14) & 1u) && neq;
            if (um || geom) key = __float_as_uint(g);   // gate >= 0 -> monotone u32
        }
        unsigned long long bm = __ballot(key > tau);
        while (bm) {
            int ln = __ffsll((long long)bm) - 1;
            bm &= bm - 1;
            unsigned kk = __shfl(key, ln, 64);
            if (kk > tau) {                    // wave-uniform
                int tk = t0 + ln;
                unsigned vprev = __shfl_up(v, 1, 64);
                int iprev = __shfl_up(vi, 1, 64);
                if (lane == 0) vprev = 0xFFFFFFFFu;
                bool keep = (v >= kk);         // equals keep -> new after (asc-t among ties)
                bool fp = (vprev < kk);
                v = keep ? v : (fp ? vprev : kk);
                vi = keep ? vi : (fp ? iprev : tk);
                tau = __shfl(v, 10, 64);
            }
        }
    }

    // Tie detect among ranks 1..11 (adjacent equal gate bits)
    unsigned vn = __shfl_down(v, 1, 64);
    bool tie = (lane < NK) && (v != 0u) && (vn == v);
    bool flag = (__ballot(tie) != 0ull);

    if (lane < NK) {
        int o = (b * NS + s) * NK + lane;
        out[NB * NS * NK + o] = 1;             // N_mask = ones always
        if (!flag) out[o] = (vi >= 0) ? vi : s;
    }
    if (lane == 0) rowflag[b * NS + s] = flag ? 1 : 0;
}

// Kernel B: slow path — exact numpy argsort(gate)[::-1][:K] for flagged rows
__global__ __launch_bounds__(256)
void span_slow_kernel(const int* __restrict__ hi, const float* __restrict__ hw,
                      const float* __restrict__ dist,
                      const unsigned char* __restrict__ capf,
                      const unsigned char* __restrict__ rowflag,
                      int* __restrict__ out) {
    __shared__ int s_any;
    __shared__ float4 s_pack[NS];
    __shared__ uint16_t s_lrc[NS];
    __shared__ float s_q[WPB][LL];
    __shared__ unsigned long long s_buf[WPB][NS];
    __shared__ int s_stk[WPB][48];

    const int b = blockIdx.x;
    if (threadIdx.x == 0) s_any = 0;
    __syncthreads();
    for (int i = threadIdx.x; i < NS; i += 256)
        if (rowflag[b * NS + i]) s_any = 1;
    __syncthreads();
    if (!s_any) return;

    stage_tables(hi + b * LL * LL * 4, hw + b * LL * LL * 4, capf + b * NS, s_pack, s_lrc);
    __syncthreads();

    const int wid = threadIdx.x >> 6;
    const int lane = threadIdx.x & 63;
    const float* db = dist + b * LL * LL;

    for (int s = wid; s < NS; s += WPB) {
        if (!rowflag[b * NS + s]) continue;

        float4 ps = s_pack[s];
        uint32_t rec = __float_as_uint(ps.w);
        int m0 = rec & 255, m1 = (rec >> 8) & 255, m2 = (rec >> 16) & 255;
        bool e1 = (m1 != 255), e2 = (m2 != 255);
        uint32_t lrc = s_lrc[s];
        int ls = lrc & 127, rs = (lrc >> 7) & 127;

        const float* row0 = db + m0 * LL;
        const float* row1 = db + (e1 ? m1 : 0) * LL;
        const float* row2 = db + (e2 ? m2 : 0) * LL;
        int mA = lane, mB = lane + 64;
        float dA0 = row0[mA], dB0 = row0[mB];
        float dA1 = row1[mA], dB1 = row1[mB];
        float dA2 = row2[mA], dB2 = row2[mB];
        float qA = __fmaf_rn(ps.x, npexp_f32(-dA0), 0.0f);
        qA = __fmaf_rn(ps.y, npexp_f32(-dA1), qA);
        qA = __fmaf_rn(ps.z, npexp_f32(-dA2), qA);
        float qB = __fmaf_rn(ps.x, npexp_f32(-dB0), 0.0f);
        qB = __fmaf_rn(ps.y, npexp_f32(-dB1), qB);
        qB = __fmaf_rn(ps.z, npexp_f32(-dB2), qB);
        bool cA = (dA0 <= 2.0f || mA == m0) ||
                  (e1 && (dA1 <= 2.0f || mA == m1)) ||
                  (e2 && (dA2 <= 2.0f || mA == m2));
        bool cB = (dB0 <= 2.0f || mB == m0) ||
                  (e1 && (dB1 <= 2.0f || mB == m1)) ||
                  (e2 && (dB2 <= 2.0f || mB == m2));
        unsigned long long ub0 = __ballot(cA);
        unsigned long long ub1 = __ballot(cB);
        s_q[wid][mA] = qA;
        s_q[wid][mB] = qB;
        wfence();
        const float* q = s_q[wid];

        for (int t0 = 0; t0 < NS; t0 += 64) {
            int t = t0 + lane;
            if (t < NS) {
                float4 pt = s_pack[t];
                uint32_t rt = __float_as_uint(pt.w);
                float g = __fmaf_rn(pt.x, q[rt & 127], 0.0f);
                g = __fmaf_rn(pt.y, q[(rt >> 8) & 127], g);
                g = __fmaf_rn(pt.z, q[(rt >> 16) & 127], g);
                uint32_t lr = s_lrc[t];
                int lt = lr & 127, rt2 = (lr >> 7) & 127;
                int dl = lt - ls; if (dl < 0) dl = -dl;
                int dr = rt2 - rs; if (dr < 0) dr = -dr;
                bool neq = (t != s);
                bool geom = neq && (dl <= 1) && (dr <= 1);
                int ri0 = rt >> 24;
                unsigned long long bits = (ri0 & 64) ? ub1 : ub0;
                bool um = (((bits >> (ri0 & 63)) & 1ull) != 0) && ((lr >> 14) & 1u) && neq;
                unsigned h32 = (um || geom) ? __float_as_uint(g) : 0xFF800000u;  // -inf
                s_buf[wid][t] = ((unsigned long long)h32 << 32) | (unsigned)t;
            }
        }
        wfence();
        wave_np_sort_top(s_buf[wid], NS, lane, s_stk[wid]);
        if (lane < NK) {
            unsigned long long k = s_buf[wid][NS - 1 - lane];  // reversed ascending
            int idx = ((unsigned)(k >> 32) == 0xFF800000u) ? s : (int)(k & 0xffffffffull);
            out[(b * NS + s) * NK + lane] = idx;
        }
        wfence();
    }
}

extern "C" void kernel_launch(void* const* d_in, const int* in_sizes, int n_in,
                              void* d_out, int out_size, void* d_ws, size_t ws_size,
                              hipStream_t stream) {
    const int* hi = (const int*)d_in[0];
    const float* hw = (const float*)d_in[1];
    const float* dist = (const float*)d_in[2];
    int* out = (int*)d_out;

    unsigned char* ws = (unsigned char*)d_ws;
    unsigned char* top1 = ws;                          // NB*NS
    unsigned char* capf = ws + NB * NS;                // NB*NS
    unsigned char* rowflag = ws + 2 * NB * NS;         // NB*NS

    int n1 = NB * NS;
    top1_kernel<<<(n1 + 255) / 256, 256, 0, stream>>>(hi, top1, capf);
    cap_kernel<<<(NB * LL * 64) / 256, 256, 0, stream>>>(top1, capf);
    dim3 grid(NS / WPB, NB);
    span_scan_kernel<<<grid, 256, 0, stream>>>(hi, hw, dist, capf, rowflag, out);
    span_slow_kernel<<<NB, 256, 0, stream>>>(hi, hw, dist, capf, rowflag, out);
}

// Round 12
// 240.167 us; speedup vs baseline: 1.5054x; 1.5054x over previous
//
#include <hip/hip_runtime.h>
#include <stdint.h>

#define NB 8
#define LL 128
#define NS 1928      // number of spans (l,r), r-l+1 <= 16
#define NK 10        // top-k
#define WPB 4        // waves (spans) per block

// span id for (l, r): offset(l) + (r-l)
__device__ __forceinline__ int span_id(int l, int r) {
    int off = (l <= 112) ? (l << 4) : (NS - (((128 - l) * (129 - l)) >> 1));
    return off + (r - l);
}

// Replica of numpy's SIMD float32 exp (verified exact vs oracle in R9/R10).
__device__ __forceinline__ float npexp_f32(float x) {
    const float magic = 12582912.0f;
    const float log2e = 1.442695040888963f;
    const float c1 = -6.93145752e-1f;
    const float c2 = -1.42860677e-6f;
    float t = __fmul_rn(x, log2e);
    float q = __fsub_rn(__fadd_rn(t, magic), magic);
    float r = __fmaf_rn(q, c1, x);
    r = __fmaf_rn(q, c2, r);
    float num = __fmaf_rn(r, 5.082762527590693718096e-04f, 6.757896990527504603057e-03f);
    num = __fmaf_rn(num, r, 5.114512081637298353406e-02f);
    num = __fmaf_rn(num, r, 2.473615434895520810817e-01f);
    num = __fmaf_rn(num, r, 7.257664613233124478488e-01f);
    num = __fmaf_rn(num, r, 9.999999999980870924916e-01f);
    float den = __fmaf_rn(r, 2.159509375685829852307e-02f, -2.742335390411667452936e-01f);
    den = __fmaf_rn(den, r, 1.0f);
    float p = __fdiv_rn(num, den);
    int qi = (int)q;
    return __fmul_rn(p, __int_as_float((127 + qi) << 23));
}

__device__ __forceinline__ float keyval(unsigned long long k) {
    return __uint_as_float((unsigned)(k >> 32));
}

__device__ __forceinline__ void wfence() {
    __builtin_amdgcn_wave_barrier();
    __threadfence_block();
    __builtin_amdgcn_wave_barrier();
}

// Wave-parallel numpy-aquicksort partition (R10-verified semantics), fast form:
// one ballot+prefix pass compacts ge/le positions into posL (asc) / posR (asc);
// swap pairs are (posL[k], posR[totLE-1-k]) while L<R; pivot -> min(posL[K], posR[totLE-K]).
__device__ int wave_partition_fast(unsigned long long* a, int* posL, int* posR,
                                   int pl, int pr, int lane) {
    int pm = pl + ((pr - pl) >> 1);
    unsigned long long vl = a[pl], vm = a[pm], vr = a[pr], tt;
    if (keyval(vm) < keyval(vl)) { tt = vm; vm = vl; vl = tt; }
    if (keyval(vr) < keyval(vm)) { tt = vr; vr = vm; vm = tt; }
    if (keyval(vm) < keyval(vl)) { tt = vm; vm = vl; vl = tt; }
    float vp = keyval(vm);
    unsigned long long vq = a[pr - 1];
    if (lane == 0) { a[pl] = vl; a[pr] = vr; a[pm] = vq; a[pr - 1] = vm; }
    wfence();

    unsigned long long lmask = (1ull << lane) - 1ull;
    int baseL = 0, baseR = 0;
    for (int p0 = pl; p0 <= pr; p0 += 64) {
        int pos = p0 + lane;
        bool inr = (pos <= pr);
        float v = inr ? keyval(a[pos]) : 0.0f;
        bool ge = inr && (pos > pl) && (pos < pr) && (v >= vp);
        bool le = inr && (pos <= pr - 2) && (v <= vp);
        unsigned long long bge = __ballot(ge);
        unsigned long long ble = __ballot(le);
        if (ge) posL[baseL + __popcll(bge & lmask)] = pos;
        if (le) posR[baseR + __popcll(ble & lmask)] = pos;
        baseL += __popcll(bge);
        baseR += __popcll(ble);
    }
    wfence();
    int totGE = baseL, totLE = baseR;
    int maxk = (totGE < totLE) ? totGE : totLE;
    int K = 0;
    for (int base = 0;; base += 64) {
        int k = base + lane;
        bool active = (k < maxk);
        int Lk = active ? posL[k] : 0x7fffffff;
        int Rk = active ? posR[totLE - 1 - k] : -1;
        bool sw = active && (Lk < Rk);
        unsigned long long bm = __ballot(sw);     // monotone prefix of true
        int nsw = (~bm == 0ull) ? 64 : (__ffsll((long long)~bm) - 1);
        if (sw && (lane < nsw)) {
            unsigned long long tl = a[Lk], tr = a[Rk];
            a[Lk] = tr; a[Rk] = tl;              // all swapped positions distinct (proof R10)
        }
        K += nsw;
        if (nsw < 64) break;
    }
    wfence();
    int pi = posL[K];                             // K < totGE (pivot at pr-1 never swapped)
    if (K > 0) { int rp = posR[totLE - K]; if (rp < pi) pi = rp; }
    if (lane == 0) { tt = a[pi]; a[pi] = a[pr - 1]; a[pr - 1] = tt; }
    wfence();
    return pi;
}

__device__ __forceinline__ void lane_sift(unsigned long long* h, int start, int hm) {
    unsigned long long tmp = h[start];
    int i = start, j = start + start;
    while (j <= hm) {
        if (j < hm && keyval(h[j]) < keyval(h[j + 1])) ++j;
        if (keyval(tmp) < keyval(h[j])) { h[i] = h[j]; i = j; j += j; }
        else break;
    }
    h[i] = tmp;
}

// numpy aheapsort on a[lo..hi], extracting only positions >= needlo.
__device__ void wave_heap_top(unsigned long long* a, int lo, int hi, int needlo, int lane) {
    unsigned long long* h = a + lo - 1;
    int hm = hi - lo + 1;
    int half = hm >> 1;
    int maxlvl = 0; { int v = half; while (v >>= 1) ++maxlvl; }
    for (int lvl = maxlvl; lvl >= 0; --lvl) {
        int n0 = 1 << lvl;
        int n1 = (n0 << 1) - 1; if (n1 > half) n1 = half;
        for (int nb = n0; nb <= n1; nb += 64) {
            int node = nb + lane;
            if (node <= n1) lane_sift(h, node, hm);
        }
        wfence();
    }
    int E = hi - needlo + 1;
    if (E > hm - 1) E = hm - 1;
    if (lane == 0) {
        int m = hm;
        for (int e = 0; e < E; ++e) {
            unsigned long long tmp = h[m]; h[m] = h[1]; --m;
            int i = 1, j = 2;
            while (j <= m) {
                if (j < m && keyval(h[j]) < keyval(h[j + 1])) ++j;
                if (keyval(tmp) < keyval(h[j])) { h[i] = h[j]; i = j; j += j; }
                else break;
            }
            h[i] = tmp;
        }
    }
    wfence();
}

// stable insertion-sort outcome via parallel stable rank (len <= 16)
__device__ void wave_insertion(unsigned long long* a, int lo, int hi, int lane) {
    int len = hi - lo + 1;
    unsigned long long v = (lane < len) ? a[lo + lane] : 0ull;
    float fv = keyval(v);
    int rank = 0;
    for (int j = 0; j < len; ++j) {
        unsigned long long vj = __shfl(v, j, 64);
        float fj = keyval(vj);
        if ((fj < fv) || (fj == fv && j < lane)) ++rank;
    }
    wfence();
    if (lane < len) a[lo + rank] = v;
    wfence();
}

// numpy introsort (verified semantics: GLOBAL depth budget, SMALL=15,
// push-larger/continue-smaller), computing only positions >= n-NK exactly.
__device__ void wave_np_sort_top(unsigned long long* a, int n, int lane, int* stk,
                                 int* posL, int* posR) {
    int depth = 0; { int v = n; while (v >>= 1) ++depth; }
    depth *= 2;
    const int TOPLO = n - NK;
    int sp = 0;
    int lo = 0, hi = n - 1;
    for (;;) {
        while (hi - lo > 15) {
            if (depth-- < 0) {
                if (hi >= TOPLO) wave_heap_top(a, lo, hi, (lo > TOPLO ? lo : TOPLO), lane);
                goto pop;
            }
            {
                int pi = wave_partition_fast(a, posL, posR, lo, hi, lane);
                if (pi - lo < hi - pi) {
                    if (lane == 0) { stk[sp * 2] = pi + 1; stk[sp * 2 + 1] = hi; }
                    ++sp; hi = pi - 1;
                } else {
                    if (lane == 0) { stk[sp * 2] = lo; stk[sp * 2 + 1] = pi - 1; }
                    ++sp; lo = pi + 1;
                }
                wfence();
            }
        }
        if (hi > lo && hi >= TOPLO) wave_insertion(a, lo, hi, lane);
pop:
        if (sp == 0) break;
        --sp;
        lo = stk[sp * 2]; hi = stk[sp * 2 + 1];
    }
}

// Kernel 1: per (b,t) extract raw top1 head index, zero flags
__global__ void top1_kernel(const int* __restrict__ hi,
                            unsigned char* __restrict__ top1,
                            unsigned char* __restrict__ flags) {
    int tid = blockIdx.x * blockDim.x + threadIdx.x;
    if (tid >= NB * NS) return;
    int b = tid / NS, t = tid - b * NS;
    int l, r;
    if (t < 1808) { l = t >> 4; r = l + (t & 15); }
    else {
        l = 113;
        while (l < 127 && span_id(l + 1, l + 1) <= t) ++l;
        r = l + (t - span_id(l, l));
    }
    int i0 = hi[((b * LL + l) * LL + r) * 4];
    top1[b * NS + t] = (unsigned char)(i0 & 127);
    flags[b * NS + t] = 0;
}

// Kernel 2: one wave per (b,l) — cumsum cap
__global__ void cap_kernel(const unsigned char* __restrict__ top1,
                           unsigned char* __restrict__ flags) {
    int gw = (blockIdx.x * blockDim.x + threadIdx.x) >> 6;
    int lane = threadIdx.x & 63;
    int b = gw >> 7, l = gw & 127;
    const unsigned char* tb = top1 + b * NS;
    unsigned char* fb = flags + b * NS;
    int cnt = 0;
    for (int t0 = 0; t0 < NS; t0 += 64) {
        int t = t0 + lane;
        int tp = (t < NS) ? (int)tb[t] : 255;
        bool match = (tp == l);
        unsigned long long m = __ballot(match);
        if (match) {
            int pre = __popcll(m & ((1ull << lane) - 1ull));
            fb[t] = (cnt + pre + 1 <= 128) ? 1 : 0;
        }
        cnt += __popcll(m);
    }
}

// Shared stage-1 staging body: pack {W0,W1,W2,rec} + lrc
__device__ __forceinline__ void stage_tables(const int* hb, const float* wb,
                                             const unsigned char* fb,
                                             float4* s_pack, uint16_t* s_lrc) {
    for (int j = threadIdx.x; j < LL * 16; j += 256) {
        int l = j >> 4, w = j & 15, r = l + w;
        if (r < LL) {
            int sid = span_id(l, r);
            int4 iv = *(const int4*)(hb + (l * LL + r) * 4);
            float4 wv = *(const float4*)(wb + (l * LL + r) * 4);
            int ia = iv.x, ib = iv.y, ic = iv.z;
            float wa = wv.x, wb2 = wv.y, wc = wv.z;
            int m0, m1 = 255, m2 = 255;
            float W0, W1 = 0.f, W2 = 0.f;
            if (ia == ib && ib == ic) {
                m0 = ia; W0 = __fadd_rn(__fadd_rn(wa, wb2), wc);
            } else if (ia == ib) {
                float W = __fadd_rn(wa, wb2);
                if (ia < ic) { m0 = ia; W0 = W; m1 = ic; W1 = wc; }
                else         { m0 = ic; W0 = wc; m1 = ia; W1 = W; }
            } else if (ia == ic) {
                float W = __fadd_rn(wa, wc);
                if (ia < ib) { m0 = ia; W0 = W; m1 = ib; W1 = wb2; }
                else         { m0 = ib; W0 = wb2; m1 = ia; W1 = W; }
            } else if (ib == ic) {
                float W = __fadd_rn(wb2, wc);
                if (ia < ib) { m0 = ia; W0 = wa; m1 = ib; W1 = W; }
                else         { m0 = ib; W0 = W; m1 = ia; W1 = wa; }
            } else {
                int x0 = ia, x1 = ib, x2 = ic; float y0 = wa, y1 = wb2, y2 = wc;
                if (x0 > x1) { int tx = x0; x0 = x1; x1 = tx; float ty = y0; y0 = y1; y1 = ty; }
                if (x1 > x2) { int tx = x1; x1 = x2; x2 = tx; float ty = y1; y1 = y2; y2 = ty; }
                if (x0 > x1) { int tx = x0; x0 = x1; x1 = tx; float ty = y0; y0 = y1; y1 = ty; }
                m0 = x0; m1 = x1; m2 = x2; W0 = y0; W1 = y1; W2 = y2;
            }
            uint32_t cap = fb[sid] & 1u;
            uint32_t rec = (uint32_t)m0 | ((uint32_t)m1 << 8) | ((uint32_t)m2 << 16)
                         | ((uint32_t)(ia & 127) << 24);
            s_pack[sid] = make_float4(W0, W1, W2, __uint_as_float(rec));
            s_lrc[sid] = (uint16_t)(l | (r << 7) | (cap << 14));
        }
    }
}

// Kernel A: fast path — lane-sorted wave top-11, flags tie rows for kernel B
__global__ __launch_bounds__(256)
void span_scan_kernel(const int* __restrict__ hi, const float* __restrict__ hw,
                      const float* __restrict__ dist,
                      const unsigned char* __restrict__ capf,
                      unsigned char* __restrict__ rowflag,
                      int* __restrict__ out) {
    __shared__ float4 s_pack[NS];
    __shared__ uint16_t s_lrc[NS];
    __shared__ float s_q[WPB][LL];

    const int b = blockIdx.y;
    stage_tables(hi + b * LL * LL * 4, hw + b * LL * LL * 4, capf + b * NS, s_pack, s_lrc);
    __syncthreads();

    const int wid = threadIdx.x >> 6;
    const int lane = threadIdx.x & 63;
    const int s = blockIdx.x * WPB + wid;

    float4 ps = s_pack[s];
    uint32_t rec = __float_as_uint(ps.w);
    int m0 = rec & 255, m1 = (rec >> 8) & 255, m2 = (rec >> 16) & 255;
    bool e1 = (m1 != 255), e2 = (m2 != 255);
    uint32_t lrc = s_lrc[s];
    int ls = lrc & 127, rs = (lrc >> 7) & 127;

    const float* db = dist + b * LL * LL;
    const float* row0 = db + m0 * LL;
    const float* row1 = db + (e1 ? m1 : 0) * LL;
    const float* row2 = db + (e2 ? m2 : 0) * LL;
    int mA = lane, mB = lane + 64;
    float dA0 = row0[mA], dB0 = row0[mB];
    float dA1 = row1[mA], dB1 = row1[mB];
    float dA2 = row2[mA], dB2 = row2[mB];
    float qA = __fmaf_rn(ps.x, npexp_f32(-dA0), 0.0f);
    qA = __fmaf_rn(ps.y, npexp_f32(-dA1), qA);
    qA = __fmaf_rn(ps.z, npexp_f32(-dA2), qA);
    float qB = __fmaf_rn(ps.x, npexp_f32(-dB0), 0.0f);
    qB = __fmaf_rn(ps.y, npexp_f32(-dB1), qB);
    qB = __fmaf_rn(ps.z, npexp_f32(-dB2), qB);
    bool cA = (dA0 <= 2.0f || mA == m0) ||
              (e1 && (dA1 <= 2.0f || mA == m1)) ||
              (e2 && (dA2 <= 2.0f || mA == m2));
    bool cB = (dB0 <= 2.0f || mB == m0) ||
              (e1 && (dB1 <= 2.0f || mB == m1)) ||
              (e2 && (dB2 <= 2.0f || mB == m2));
    unsigned long long ub0 = __ballot(cA);
    unsigned long long ub1 = __ballot(cB);
    s_q[wid][mA] = qA;
    s_q[wid][mB] = qB;
    const float* q = s_q[wid];

    // scan with wave-cooperative sorted top-11 (one rank per lane, desc)
    unsigned v = 0u; int vi = -1; unsigned tau = 0u;

    for (int t0 = 0; t0 < NS; t0 += 64) {
        int t = t0 + lane;
        unsigned key = 0u;
        if (t < NS) {
            float4 pt = s_pack[t];
            uint32_t rt = __float_as_uint(pt.w);
            float g = __fmaf_rn(pt.x, q[rt & 127], 0.0f);
            g = __fmaf_rn(pt.y, q[(rt >> 8) & 127], g);
            g = __fmaf_rn(pt.z, q[(rt >> 16) & 127], g);
            uint32_t lr = s_lrc[t];
            int lt = lr & 127, rt2 = (lr >> 7) & 127;
            int dl = lt - ls; if (dl < 0) dl = -dl;
            int dr = rt2 - rs; if (dr < 0) dr = -dr;
            bool neq = (t != s);
            bool geom = neq && (dl <= 1) && (dr <= 1);
            int ri0 = rt >> 24;
            unsigned long long bits = (ri0 & 64) ? ub1 : ub0;
            bool um = (((bits >> (ri0 & 63)) & 1ull) != 0) && ((lr >> 14) & 1u) && neq;
            if (um || geom) key = __float_as_uint(g);   // gate >= 0 -> monotone u32
        }
        unsigned long long bm = __ballot(key > tau);
        while (bm) {
            int ln = __ffsll((long long)bm) - 1;
            bm &= bm - 1;
            unsigned kk = __shfl(key, ln, 64);
            if (kk > tau) {                    // wave-uniform
                int tk = t0 + ln;
                unsigned vprev = __shfl_up(v, 1, 64);
                int iprev = __shfl_up(vi, 1, 64);
                if (lane == 0) vprev = 0xFFFFFFFFu;
                bool keep = (v >= kk);         // equals keep -> new after (asc-t among ties)
                bool fp = (vprev < kk);
                v = keep ? v : (fp ? vprev : kk);
                vi = keep ? vi : (fp ? iprev : tk);
                tau = __shfl(v, 10, 64);
            }
        }
    }

    unsigned vn = __shfl_down(v, 1, 64);
    bool tie = (lane < NK) && (v != 0u) && (vn == v);
    bool flag = (__ballot(tie) != 0ull);

    if (lane < NK) {
        int o = (b * NS + s) * NK + lane;
        out[NB * NS * NK + o] = 1;             // N_mask = ones always
        if (!flag) out[o] = (vi >= 0) ? vi : s;
    }
    if (lane == 0) rowflag[b * NS + s] = flag ? 1 : 0;
}

// Kernel B: slow path — exact numpy argsort(gate)[::-1][:K] for flagged rows.
// Block-shared buffers; all 256 threads fill gates, wave 0 runs the sort.
__global__ __launch_bounds__(256)
void span_slow_kernel(const int* __restrict__ hi, const float* __restrict__ hw,
                      const float* __restrict__ dist,
                      const unsigned char* __restrict__ capf,
                      const unsigned char* __restrict__ rowflag,
                      int* __restrict__ out) {
    __shared__ int s_nrows;
    __shared__ int s_rows[256];
    __shared__ float4 s_pack[NS];
    __shared__ uint16_t s_lrc[NS];
    __shared__ float s_qq[LL];
    __shared__ unsigned long long s_cov[2];
    __shared__ unsigned long long s_buf[NS];
    __shared__ int s_posL[NS], s_posR[NS];
    __shared__ int s_stk[48];

    const int b = blockIdx.x;
    if (threadIdx.x == 0) s_nrows = 0;
    __syncthreads();
    for (int i = threadIdx.x; i < NS; i += 256) {
        if (rowflag[b * NS + i]) {
            int k = atomicAdd(&s_nrows, 1);
            if (k < 256) s_rows[k] = i;
        }
    }
    __syncthreads();
    int nrows = s_nrows; if (nrows > 256) nrows = 256;
    if (nrows == 0) return;

    stage_tables(hi + b * LL * LL * 4, hw + b * LL * LL * 4, capf + b * NS, s_pack, s_lrc);
    __syncthreads();

    const int wid = threadIdx.x >> 6;
    const int lane = threadIdx.x & 63;
    const float* db = dist + b * LL * LL;

    for (int ri = 0; ri < nrows; ++ri) {
        const int s = s_rows[ri];
        uint32_t lrc = s_lrc[s];
        int ls = lrc & 127, rs = (lrc >> 7) & 127;

        if (wid == 0) {   // wave 0: q row + coverage ballots
            float4 ps = s_pack[s];
            uint32_t rec = __float_as_uint(ps.w);
            int m0 = rec & 255, m1 = (rec >> 8) & 255, m2 = (rec >> 16) & 255;
            bool e1 = (m1 != 255), e2 = (m2 != 255);
            const float* row0 = db + m0 * LL;
            const float* row1 = db + (e1 ? m1 : 0) * LL;
            const float* row2 = db + (e2 ? m2 : 0) * LL;
            int mA = lane, mB = lane + 64;
            float dA0 = row0[mA], dB0 = row0[mB];
            float dA1 = row1[mA], dB1 = row1[mB];
            float dA2 = row2[mA], dB2 = row2[mB];
            float qA = __fmaf_rn(ps.x, npexp_f32(-dA0), 0.0f);
            qA = __fmaf_rn(ps.y, npexp_f32(-dA1), qA);
            qA = __fmaf_rn(ps.z, npexp_f32(-dA2), qA);
            float qB = __fmaf_rn(ps.x, npexp_f32(-dB0), 0.0f);
            qB = __fmaf_rn(ps.y, npexp_f32(-dB1), qB);
            qB = __fmaf_rn(ps.z, npexp_f32(-dB2), qB);
            bool cA = (dA0 <= 2.0f || mA == m0) ||
                      (e1 && (dA1 <= 2.0f || mA == m1)) ||
                      (e2 && (dA2 <= 2.0f || mA == m2));
            bool cB = (dB0 <= 2.0f || mB == m0) ||
                      (e1 && (dB1 <= 2.0f || mB == m1)) ||
                      (e2 && (dB2 <= 2.0f || mB == m2));
            unsigned long long u0 = __ballot(cA);
            unsigned long long u1 = __ballot(cB);
            s_qq[mA] = qA;
            s_qq[mB] = qB;
            if (lane == 0) { s_cov[0] = u0; s_cov[1] = u1; }
        }
        __syncthreads();
        unsigned long long ub0 = s_cov[0], ub1 = s_cov[1];

        for (int t = threadIdx.x; t < NS; t += 256) {   // all threads: gate fill
            float4 pt = s_pack[t];
            uint32_t rt = __float_as_uint(pt.w);
            float g = __fmaf_rn(pt.x, s_qq[rt & 127], 0.0f);
            g = __fmaf_rn(pt.y, s_qq[(rt >> 8) & 127], g);
            g = __fmaf_rn(pt.z, s_qq[(rt >> 16) & 127], g);
            uint32_t lr = s_lrc[t];
            int lt = lr & 127, rt2 = (lr >> 7) & 127;
            int dl = lt - ls; if (dl < 0) dl = -dl;
            int dr = rt2 - rs; if (dr < 0) dr = -dr;
            bool neq = (t != s);
            bool geom = neq && (dl <= 1) && (dr <= 1);
            int ri0 = rt >> 24;
            unsigned long long bits = (ri0 & 64) ? ub1 : ub0;
            bool um = (((bits >> (ri0 & 63)) & 1ull) != 0) && ((lr >> 14) & 1u) && neq;
            unsigned h32 = (um || geom) ? __float_as_uint(g) : 0xFF800000u;  // -inf
            s_buf[t] = ((unsigned long long)h32 << 32) | (unsigned)t;
        }
        __syncthreads();

        if (wid == 0) {
            wave_np_sort_top(s_buf, NS, lane, s_stk, s_posL, s_posR);
            if (lane < NK) {
                unsigned long long k = s_buf[NS - 1 - lane];  // reversed ascending
                int idx = ((unsigned)(k >> 32) == 0xFF800000u) ? s : (int)(k & 0xffffffffull);
                out[(b * NS + s) * NK + lane] = idx;
            }
        }
        __syncthreads();
    }
}

extern "C" void kernel_launch(void* const* d_in, const int* in_sizes, int n_in,
                              void* d_out, int out_size, void* d_ws, size_t ws_size,
                              hipStream_t stream) {
    const int* hi = (const int*)d_in[0];
    const float* hw = (const float*)d_in[1];
    const float* dist = (const float*)d_in[2];
    int* out = (int*)d_out;

    unsigned char* ws = (unsigned char*)d_ws;
    unsigned char* top1 = ws;                          // NB*NS
    unsigned char* capf = ws + NB * NS;                // NB*NS
    unsigned char* rowflag = ws + 2 * NB * NS;         // NB*NS

    int n1 = NB * NS;
    top1_kernel<<<(n1 + 255) / 256, 256, 0, stream>>>(hi, top1, capf);
    cap_kernel<<<(NB * LL * 64) / 256, 256, 0, stream>>>(top1, capf);
    dim3 grid(NS / WPB, NB);
    span_scan_kernel<<<grid, 256, 0, stream>>>(hi, hw, dist, capf, rowflag, out);
    span_slow_kernel<<<NB, 256, 0, stream>>>(hi, hw, dist, capf, rowflag, out);
}